// Round 1
// baseline (689.422 us; speedup 1.0000x reference)
//
#include <hip/hip_runtime.h>
#include <stdint.h>

typedef unsigned short u16;
typedef unsigned int u32;
typedef __bf16 bf16x8 __attribute__((ext_vector_type(8)));
typedef float f32x4 __attribute__((ext_vector_type(4)));

__device__ __forceinline__ u16 f2bf(float x){
  u32 u = __float_as_uint(x);
  u += 0x7FFFu + ((u >> 16) & 1u);
  return (u16)(u >> 16);
}
__device__ __forceinline__ float bf2f(u16 h){
  return __uint_as_float(((u32)h) << 16);
}
__device__ __forceinline__ f32x4 mfma16(bf16x8 a, bf16x8 b, f32x4 c){
  return __builtin_amdgcn_mfma_f32_16x16x32_bf16(a, b, c, 0, 0, 0);
}

// ---------------- RoPE table: cos/sin[p][i], p<2048, i<64 ----------------
__global__ void k_rope_table(float* __restrict__ ct, float* __restrict__ st){
  int idx = blockIdx.x * 256 + threadIdx.x;   // 2048*64 total
  int p = idx >> 6, i = idx & 63;
  float freq = powf(10000.0f, -(float)i / 64.0f);
  float ang = (float)p * freq;
  ct[idx] = cosf(ang);
  st[idx] = sinf(ang);
}

// ---------------- f32 -> bf16 cast (4 elems/thread) ----------------
__global__ void k_cast_bf16(const float* __restrict__ in, u16* __restrict__ out){
  int i = (blockIdx.x * 256 + threadIdx.x) * 4;
  float4 v = *(const float4*)(in + i);
  ushort4 o;
  o.x = f2bf(v.x); o.y = f2bf(v.y); o.z = f2bf(v.z); o.w = f2bf(v.w);
  *(ushort4*)(out + i) = o;
}

// ------- transpose+cast combined [2048 k][Wq|Wk|Wv cols] -> out[n][k] bf16 -------
__global__ void k_trans_qkv(const float* __restrict__ Wq, const float* __restrict__ Wk,
                            const float* __restrict__ Wv, u16* __restrict__ out){
  __shared__ float tile[32][33];
  int nb = blockIdx.x * 32, kb = blockIdx.y * 32;
  int tx = threadIdx.x, ty = threadIdx.y;      // (32,8)
  #pragma unroll
  for (int j = 0; j < 4; j++){
    int k = kb + ty + j*8;
    int n = nb + tx;
    float v;
    if (n < 2048)      v = Wq[(size_t)k*2048 + n];
    else if (n < 2560) v = Wk[(size_t)k*512 + (n - 2048)];
    else               v = Wv[(size_t)k*512 + (n - 2560)];
    tile[tx][ty + j*8] = v;
  }
  __syncthreads();
  #pragma unroll
  for (int j = 0; j < 4; j++){
    int n = nb + ty + j*8;
    out[(size_t)n*2048 + kb + tx] = f2bf(tile[ty + j*8][tx]);
  }
}

__global__ void k_trans_wc(const float* __restrict__ Wc, u16* __restrict__ out){
  __shared__ float tile[32][33];
  int nb = blockIdx.x * 32, kb = blockIdx.y * 32;
  int tx = threadIdx.x, ty = threadIdx.y;
  #pragma unroll
  for (int j = 0; j < 4; j++){
    tile[tx][ty + j*8] = Wc[(size_t)(kb + ty + j*8)*2048 + nb + tx];
  }
  __syncthreads();
  #pragma unroll
  for (int j = 0; j < 4; j++){
    out[(size_t)(nb + ty + j*8)*2048 + kb + tx] = f2bf(tile[ty + j*8][tx]);
  }
}

// ---------------- GEMM: C[m][n] = sum_k A[m][k]*Bt[n][k], bf16 in, tile 128x128 ----------------
#define ASTR 40   // LDS row stride (elems): 80B = 20 banks -> 2-way conflicts (free)
template<bool OBF>
__global__ __launch_bounds__(256) void k_gemm(const u16* __restrict__ A, const u16* __restrict__ Bt,
                                              void* __restrict__ Cv, int M, int N, int K){
  __shared__ u16 As[128*ASTR], Bs[128*ASTR];
  int tid = threadIdx.x;
  int lane = tid & 63, w = tid >> 6;
  int g = lane >> 4, c16 = lane & 15;
  int wr = w >> 1, wc = w & 1;
  size_t bm = (size_t)blockIdx.y * 128, bn = (size_t)blockIdx.x * 128;
  f32x4 zero = {0.f, 0.f, 0.f, 0.f};
  f32x4 acc[4][4];
  #pragma unroll
  for (int i=0;i<4;i++)
    #pragma unroll
    for (int j=0;j<4;j++) acc[i][j] = zero;
  int sr = tid >> 1, scc = (tid & 1) * 16;
  const u16* Ag = A + (bm + sr) * (size_t)K + scc;
  const u16* Bg = Bt + (bn + sr) * (size_t)K + scc;
  u16* Asw = &As[sr*ASTR + scc];
  u16* Bsw = &Bs[sr*ASTR + scc];
  for (int k0 = 0; k0 < K; k0 += 32){
    uint4 a0 = *(const uint4*)(Ag + k0);
    uint4 a1 = *(const uint4*)(Ag + k0 + 8);
    uint4 b0 = *(const uint4*)(Bg + k0);
    uint4 b1 = *(const uint4*)(Bg + k0 + 8);
    __syncthreads();
    *(uint4*)(Asw) = a0; *(uint4*)(Asw + 8) = a1;
    *(uint4*)(Bsw) = b0; *(uint4*)(Bsw + 8) = b1;
    __syncthreads();
    bf16x8 af[4], bfr[4];
    #pragma unroll
    for (int mi=0;mi<4;mi++) af[mi]  = *(const bf16x8*)&As[(wr*64 + mi*16 + c16)*ASTR + g*8];
    #pragma unroll
    for (int ni=0;ni<4;ni++) bfr[ni] = *(const bf16x8*)&Bs[(wc*64 + ni*16 + c16)*ASTR + g*8];
    #pragma unroll
    for (int mi=0;mi<4;mi++)
      #pragma unroll
      for (int ni=0;ni<4;ni++)
        acc[mi][ni] = mfma16(af[mi], bfr[ni], acc[mi][ni]);
  }
  #pragma unroll
  for (int mi=0;mi<4;mi++){
    #pragma unroll
    for (int ni=0;ni<4;ni++){
      #pragma unroll
      for (int r=0;r<4;r++){
        size_t row = bm + wr*64 + mi*16 + g*4 + r;
        size_t col = bn + wc*64 + ni*16 + c16;
        if (OBF) ((u16*)Cv)[row * (size_t)N + col] = f2bf(acc[mi][ni][r]);
        else     ((float*)Cv)[row * (size_t)N + col] = acc[mi][ni][r];
      }
    }
  }
}

// ---------------- RMSNorm + RoPE + layout. 1 wave per (b,s,head-slot) ----------------
// slots: 0..15 q heads -> qo[B,NH,S,HD]; 16..19 k heads -> ko[B,NKV,S,HD];
// 20..23 v heads -> vt[B,NKV,HD,S] (transposed copy, no norm)
__global__ __launch_bounds__(64) void k_norm_rope(const u16* __restrict__ qkv, const int* __restrict__ pos,
    const float* __restrict__ qsc, const float* __restrict__ ksc,
    const float* __restrict__ ct, const float* __restrict__ st,
    u16* __restrict__ qo, u16* __restrict__ ko, u16* __restrict__ vt){
  int bs = blockIdx.x, hh = blockIdx.y, d = threadIdx.x;
  int b = bs >> 11, s = bs & 2047;
  const u16* row = qkv + (size_t)bs * 3072 + hh * 128;
  u16 r1 = row[d], r2 = row[d + 64];
  if (hh >= 20){
    int kvh = hh - 20;
    size_t base = ((size_t)(b*4 + kvh)) * 128;
    vt[(base + d) * 2048 + s] = r1;
    vt[(base + d + 64) * 2048 + s] = r2;
    return;
  }
  float x1 = bf2f(r1), x2 = bf2f(r2);
  float ssq = x1*x1 + x2*x2;
  #pragma unroll
  for (int mm = 1; mm < 64; mm <<= 1) ssq += __shfl_xor(ssq, mm);
  float inv = rsqrtf(ssq * (1.0f/128.0f) + 1e-6f);
  const float* sc = (hh < 16) ? qsc : ksc;
  float y1 = x1 * inv * sc[d];
  float y2 = x2 * inv * sc[d + 64];
  int p = pos[bs];
  float c = ct[p*64 + d], sn = st[p*64 + d];
  float o1 = y1*c - y2*sn;
  float o2 = y2*c + y1*sn;
  if (hh < 16){
    size_t o = ((size_t)(b*16 + hh) * 2048 + s) * 128 + d;
    qo[o] = f2bf(o1); qo[o + 64] = f2bf(o2);
  } else {
    size_t o = ((size_t)(b*4 + (hh-16)) * 2048 + s) * 128 + d;
    ko[o] = f2bf(o1); ko[o + 64] = f2bf(o2);
  }
}

// ---------------- flash attention, causal, GQA 16q/4kv, HD=128 ----------------
// block = 4 waves; wave w owns 16 q rows; KV tile = 64. P via per-wave swizzled LDS.
__global__ __launch_bounds__(256) void k_attn(const u16* __restrict__ q, const u16* __restrict__ k,
    const u16* __restrict__ vt, u16* __restrict__ attn){
  __shared__ u16 P[4][16][64];
  int lane = threadIdx.x & 63, w = threadIdx.x >> 6;
  int g = lane >> 4, c16 = lane & 15;
  int qb = blockIdx.x * 64, h = blockIdx.y, b = blockIdx.z, kvh = h >> 2;
  const u16* qp = q + ((size_t)(b*16 + h)) * 2048 * 128;
  const u16* kp = k + ((size_t)(b*4 + kvh)) * 2048 * 128;
  const u16* vp = vt + ((size_t)(b*4 + kvh)) * 128 * 2048;
  int qrow = qb + w*16 + c16;
  bf16x8 qf[4];
  #pragma unroll
  for (int kk = 0; kk < 4; kk++)
    qf[kk] = *(const bf16x8*)(qp + (size_t)qrow*128 + kk*32 + g*8);
  f32x4 zero = {0.f,0.f,0.f,0.f};
  f32x4 o[8];
  #pragma unroll
  for (int i=0;i<8;i++) o[i] = zero;
  float m[4] = {-1e30f,-1e30f,-1e30f,-1e30f};
  float l[4] = {0.f,0.f,0.f,0.f};
  int rq[4];
  #pragma unroll
  for (int r=0;r<4;r++) rq[r] = qb + w*16 + g*4 + r;
  const float scale = 0.08838834764831845f;  // 128^-0.5
  int nt_iters = (qb >> 6) + 1;
  for (int t = 0; t < nt_iters; t++){
    int c0 = t * 64;
    f32x4 sacc[4];
    #pragma unroll
    for (int i=0;i<4;i++) sacc[i] = zero;
    #pragma unroll
    for (int nt=0;nt<4;nt++){
      const u16* kr = kp + (size_t)(c0 + nt*16 + c16)*128 + g*8;
      #pragma unroll
      for (int kk=0;kk<4;kk++){
        bf16x8 kf = *(const bf16x8*)(kr + kk*32);
        sacc[nt] = mfma16(qf[kk], kf, sacc[nt]);
      }
    }
    float alpha[4];
    #pragma unroll
    for (int r=0;r<4;r++){
      float mx = -1e30f;
      #pragma unroll
      for (int nt=0;nt<4;nt++){
        float sv = sacc[nt][r] * scale;
        if (c0 + nt*16 + c16 > rq[r]) sv = -1e30f;
        sacc[nt][r] = sv;
        mx = fmaxf(mx, sv);
      }
      mx = fmaxf(mx, __shfl_xor(mx, 1));
      mx = fmaxf(mx, __shfl_xor(mx, 2));
      mx = fmaxf(mx, __shfl_xor(mx, 4));
      mx = fmaxf(mx, __shfl_xor(mx, 8));
      float mn = fmaxf(m[r], mx);
      alpha[r] = __expf(m[r] - mn);
      float sum = 0.f;
      #pragma unroll
      for (int nt=0;nt<4;nt++){
        float p = __expf(sacc[nt][r] - mn);
        sacc[nt][r] = p;
        sum += p;
      }
      sum += __shfl_xor(sum, 1);
      sum += __shfl_xor(sum, 2);
      sum += __shfl_xor(sum, 4);
      sum += __shfl_xor(sum, 8);
      l[r] = l[r]*alpha[r] + sum;
      m[r] = mn;
    }
    #pragma unroll
    for (int dt=0;dt<8;dt++)
      #pragma unroll
      for (int r=0;r<4;r++) o[dt][r] *= alpha[r];
    // write P, XOR-swizzled on 8-elem (16B) blocks; per-wave buffer -> no barrier
    // (same-wave DS ops execute in order)
    #pragma unroll
    for (int nt=0;nt<4;nt++){
      #pragma unroll
      for (int r=0;r<4;r++){
        int row = g*4 + r;
        int col = (nt*16 + c16) ^ ((row & 7) << 3);
        P[w][row][col] = f2bf(sacc[nt][r]);
      }
    }
    // PV: A = P rows (row = c16), B = Vt rows (d = dt*16+c16)
    #pragma unroll
    for (int kk2=0;kk2<2;kk2++){
      int cb = (kk2*4 + g) ^ (c16 & 7);
      bf16x8 pf = *(const bf16x8*)&P[w][c16][cb * 8];
      const u16* vr = vp + c0 + kk2*32 + g*8;
      #pragma unroll
      for (int dt=0;dt<8;dt++){
        bf16x8 vf = *(const bf16x8*)(vr + (size_t)(dt*16 + c16) * 2048);
        o[dt] = mfma16(pf, vf, o[dt]);
      }
    }
  }
  #pragma unroll
  for (int dt=0;dt<8;dt++){
    #pragma unroll
    for (int r=0;r<4;r++){
      size_t orow = (size_t)b*2048 + qb + w*16 + g*4 + r;
      attn[orow*2048 + (size_t)h*128 + dt*16 + c16] = f2bf(o[dt][r] / l[r]);
    }
  }
}

extern "C" void kernel_launch(void* const* d_in, const int* in_sizes, int n_in,
                              void* d_out, int out_size, void* d_ws, size_t ws_size,
                              hipStream_t stream){
  const float* hidden    = (const float*)d_in[0];
  const int*   positions = (const int*)d_in[1];
  const float* Wq = (const float*)d_in[2];
  const float* Wk = (const float*)d_in[3];
  const float* Wv = (const float*)d_in[4];
  const float* Wc = (const float*)d_in[5];
  const float* qs = (const float*)d_in[6];
  const float* ks = (const float*)d_in[7];
  float* out = (float*)d_out;
  char* ws = (char*)d_ws;
  // workspace layout (bytes). attn_bf reuses hid_bf's region (dead by then).
  float* ct      = (float*)(ws + 0);          // 2048*64*4   = 524288
  float* st      = (float*)(ws + 524288);     //             -> 1048576
  u16*   hid_bf  = (u16*)(ws + 1048576);      // 4096*2048*2 -> 17825792
  u16*   attn_bf = hid_bf;                    // reuse
  u16*   wqkv_t  = (u16*)(ws + 17825792);     // 3072*2048*2 -> 30408704
  u16*   wct     = (u16*)(ws + 30408704);     // 2048*2048*2 -> 38797312
  u16*   qkv_bf  = (u16*)(ws + 38797312);     // 4096*3072*2 -> 63963136
  u16*   q_bf    = (u16*)(ws + 63963136);     // 2*16*2048*128*2 -> 80740352
  u16*   k_bf    = (u16*)(ws + 80740352);     // 2*4*2048*128*2  -> 84934656
  u16*   vt_bf   = (u16*)(ws + 84934656);     // 2*4*128*2048*2  -> 89128960

  k_rope_table<<<512, 256, 0, stream>>>(ct, st);
  k_cast_bf16<<<8192, 256, 0, stream>>>(hidden, hid_bf);
  k_trans_qkv<<<dim3(96, 64), dim3(32, 8), 0, stream>>>(Wq, Wk, Wv, wqkv_t);
  k_trans_wc<<<dim3(64, 64), dim3(32, 8), 0, stream>>>(Wc, wct);
  k_gemm<true><<<dim3(24, 32), 256, 0, stream>>>(hid_bf, wqkv_t, (void*)qkv_bf, 4096, 3072, 2048);
  k_norm_rope<<<dim3(4096, 24), 64, 0, stream>>>(qkv_bf, positions, qs, ks, ct, st, q_bf, k_bf, vt_bf);
  k_attn<<<dim3(32, 16, 2), 256, 0, stream>>>(q_bf, k_bf, vt_bf, attn_bf);
  k_gemm<false><<<dim3(16, 32), 256, 0, stream>>>(attn_bf, wct, (void*)out, 4096, 2048, 2048);
}

// Round 2
// 284.977 us; speedup vs baseline: 2.4192x; 2.4192x over previous
//
#include <hip/hip_runtime.h>
#include <stdint.h>

typedef unsigned short u16;
typedef unsigned int u32;
typedef __bf16 bf16x8 __attribute__((ext_vector_type(8)));
typedef float f32x4 __attribute__((ext_vector_type(4)));

__device__ __forceinline__ u16 f2bf(float x){
  u32 u = __float_as_uint(x);
  u += 0x7FFFu + ((u >> 16) & 1u);
  return (u16)(u >> 16);
}
__device__ __forceinline__ float bf2f(u16 h){
  return __uint_as_float(((u32)h) << 16);
}
__device__ __forceinline__ f32x4 mfma16(bf16x8 a, bf16x8 b, f32x4 c){
  return __builtin_amdgcn_mfma_f32_16x16x32_bf16(a, b, c, 0, 0, 0);
}
// async global->LDS, 16B per lane. LDS dest = wave-uniform base + lane*16.
// AS(3) pointer = low 32 bits of flat shared pointer; AS(1) = flat global bits.
__device__ __forceinline__ void gload16(const void* g, const void* l){
  __builtin_amdgcn_global_load_lds(
      (__attribute__((address_space(1))) void*)(uintptr_t)g,
      (__attribute__((address_space(3))) void*)(u32)(uintptr_t)l,
      16, 0, 0);
}

// ---------------- RoPE table: cos/sin[p][i], p<2048, i<64 ----------------
__global__ void k_rope_table(float* __restrict__ ct, float* __restrict__ st){
  int idx = blockIdx.x * 256 + threadIdx.x;
  int p = idx >> 6, i = idx & 63;
  float freq = powf(10000.0f, -(float)i / 64.0f);
  float ang = (float)p * freq;
  ct[idx] = cosf(ang);
  st[idx] = sinf(ang);
}

// ---------------- f32 -> bf16 cast ----------------
__global__ void k_cast_bf16(const float* __restrict__ in, u16* __restrict__ out){
  int i = (blockIdx.x * 256 + threadIdx.x) * 4;
  float4 v = *(const float4*)(in + i);
  ushort4 o;
  o.x = f2bf(v.x); o.y = f2bf(v.y); o.z = f2bf(v.z); o.w = f2bf(v.w);
  *(ushort4*)(out + i) = o;
}

// ------- transpose+cast [2048 k][Wq|Wk|Wv cols] -> out[n][k] bf16 -------
__global__ void k_trans_qkv(const float* __restrict__ Wq, const float* __restrict__ Wk,
                            const float* __restrict__ Wv, u16* __restrict__ out){
  __shared__ float tile[32][33];
  int nb = blockIdx.x * 32, kb = blockIdx.y * 32;
  int tx = threadIdx.x, ty = threadIdx.y;
  #pragma unroll
  for (int j = 0; j < 4; j++){
    int k = kb + ty + j*8;
    int n = nb + tx;
    float v;
    if (n < 2048)      v = Wq[(size_t)k*2048 + n];
    else if (n < 2560) v = Wk[(size_t)k*512 + (n - 2048)];
    else               v = Wv[(size_t)k*512 + (n - 2560)];
    tile[tx][ty + j*8] = v;
  }
  __syncthreads();
  #pragma unroll
  for (int j = 0; j < 4; j++){
    int n = nb + ty + j*8;
    out[(size_t)n*2048 + kb + tx] = f2bf(tile[ty + j*8][tx]);
  }
}

__global__ void k_trans_wc(const float* __restrict__ Wc, u16* __restrict__ out){
  __shared__ float tile[32][33];
  int nb = blockIdx.x * 32, kb = blockIdx.y * 32;
  int tx = threadIdx.x, ty = threadIdx.y;
  #pragma unroll
  for (int j = 0; j < 4; j++){
    tile[tx][ty + j*8] = Wc[(size_t)(kb + ty + j*8)*2048 + nb + tx];
  }
  __syncthreads();
  #pragma unroll
  for (int j = 0; j < 4; j++){
    out[(size_t)(nb + ty + j*8)*2048 + kb + tx] = f2bf(tile[ty + j*8][tx]);
  }
}

// ------- GEMM (m97 structure): C[m][n] = sum_k A[m][k]*Bt[n][k], 128x128 tile, BK=32,
// global_load_lds width-16 staging into linear [128][32] LDS, 2 barriers per K-step -------
template<bool OBF>
__global__ __launch_bounds__(256) void k_gemm(const u16* __restrict__ A, const u16* __restrict__ Bt,
                                              void* __restrict__ Cv, int M, int N, int K){
  __shared__ u16 As[128*32], Bs[128*32];
  int tid = threadIdx.x;
  int lane = tid & 63, w = tid >> 6;
  int g = lane >> 4, c16 = lane & 15;
  int wr = w >> 1, wc = w & 1;
  size_t bm = (size_t)blockIdx.y * 128, bn = (size_t)blockIdx.x * 128;
  f32x4 zero = {0.f, 0.f, 0.f, 0.f};
  f32x4 acc[4][4];
  #pragma unroll
  for (int i=0;i<4;i++)
    #pragma unroll
    for (int j=0;j<4;j++) acc[i][j] = zero;
  for (int k0 = 0; k0 < K; k0 += 32){
    #pragma unroll
    for (int p = 0; p < 2; p++){
      int j = (w*2 + p)*64 + lane;     // 0..511 chunks of 16B
      int r = j >> 2, slot = j & 3;    // row 0..127, 4 chunks per 32-elem row
      gload16(A  + (bm + r)*(size_t)K + k0 + slot*8, (const char*)As + (w*2+p)*1024);
      gload16(Bt + (bn + r)*(size_t)K + k0 + slot*8, (const char*)Bs + (w*2+p)*1024);
    }
    __syncthreads();   // drains vmcnt(0): tile landed; all waves aligned
    bf16x8 af[4], bfr[4];
    #pragma unroll
    for (int mi=0;mi<4;mi++) af[mi]  = *(const bf16x8*)&As[(wr*64 + mi*16 + c16)*32 + g*8];
    #pragma unroll
    for (int ni=0;ni<4;ni++) bfr[ni] = *(const bf16x8*)&Bs[(wc*64 + ni*16 + c16)*32 + g*8];
    #pragma unroll
    for (int mi=0;mi<4;mi++)
      #pragma unroll
      for (int ni=0;ni<4;ni++)
        acc[mi][ni] = mfma16(af[mi], bfr[ni], acc[mi][ni]);
    __syncthreads();   // reads done before next stage overwrites
  }
  #pragma unroll
  for (int mi=0;mi<4;mi++){
    #pragma unroll
    for (int ni=0;ni<4;ni++){
      #pragma unroll
      for (int r=0;r<4;r++){
        size_t row = bm + wr*64 + mi*16 + g*4 + r;
        size_t col = bn + wc*64 + ni*16 + c16;
        if (OBF) ((u16*)Cv)[row * (size_t)N + col] = f2bf(acc[mi][ni][r]);
        else     ((float*)Cv)[row * (size_t)N + col] = acc[mi][ni][r];
      }
    }
  }
}

// ---------------- RMSNorm + RoPE + layout ----------------
__global__ __launch_bounds__(64) void k_norm_rope(const u16* __restrict__ qkv, const int* __restrict__ pos,
    const float* __restrict__ qsc, const float* __restrict__ ksc,
    const float* __restrict__ ct, const float* __restrict__ st,
    u16* __restrict__ qo, u16* __restrict__ ko, u16* __restrict__ vt){
  int bs = blockIdx.x, hh = blockIdx.y, d = threadIdx.x;
  int b = bs >> 11, s = bs & 2047;
  const u16* row = qkv + (size_t)bs * 3072 + hh * 128;
  u16 r1 = row[d], r2 = row[d + 64];
  if (hh >= 20){
    int kvh = hh - 20;
    size_t base = ((size_t)(b*4 + kvh)) * 128;
    vt[(base + d) * 2048 + s] = r1;
    vt[(base + d + 64) * 2048 + s] = r2;
    return;
  }
  float x1 = bf2f(r1), x2 = bf2f(r2);
  float ssq = x1*x1 + x2*x2;
  #pragma unroll
  for (int mm = 1; mm < 64; mm <<= 1) ssq += __shfl_xor(ssq, mm);
  float inv = rsqrtf(ssq * (1.0f/128.0f) + 1e-6f);
  const float* sc = (hh < 16) ? qsc : ksc;
  float y1 = x1 * inv * sc[d];
  float y2 = x2 * inv * sc[d + 64];
  int p = pos[bs];
  float c = ct[p*64 + d], sn = st[p*64 + d];
  float o1 = y1*c - y2*sn;
  float o2 = y2*c + y1*sn;
  if (hh < 16){
    size_t o = ((size_t)(b*16 + hh) * 2048 + s) * 128 + d;
    qo[o] = f2bf(o1); qo[o + 64] = f2bf(o2);
  } else {
    size_t o = ((size_t)(b*4 + (hh-16)) * 2048 + s) * 128 + d;
    ko[o] = f2bf(o1); ko[o + 64] = f2bf(o2);
  }
}

// ---------------- flash attention, causal, GQA, paired q-blocks + LDS-staged KV ----------------
// Block = 4 waves (256 thr). Block owns q-blocks pi (group A) and 31-pi (group B), 64 rows each;
// wave w owns rows [qb + w*16, +16) of each. KV tiles of 64 staged in LDS (dbuf) via
// global_load_lds; counted vmcnt(8) + raw s_barrier 2-phase pipeline. Every block = 33 tile-units.
__device__ __forceinline__ void stage_kv(int w, int lane, u16* ksb, u16* vsb,
                                         const u16* kp, const u16* vp, int c0){
  // K: [64 r][128 elems], 16B slot s stores cols ((s^(r&7))*8 ..+8)
  #pragma unroll
  for (int p = 0; p < 4; p++){
    int j = (w*4 + p)*64 + lane;     // 0..1023
    int r = j >> 4, slot = j & 15;
    const u16* src = kp + (size_t)(c0 + r)*128 + ((slot ^ (r & 7)) << 3);
    gload16(src, (const char*)ksb + (w*4 + p)*1024);
  }
  // V^T: [128 d][64 cols], 16B slot s stores cols ((s^(d&7))*8 ..+8)
  #pragma unroll
  for (int p = 0; p < 4; p++){
    int j = (w*4 + p)*64 + lane;
    int r = j >> 3, slot = j & 7;
    const u16* src = vp + (size_t)r*2048 + c0 + ((slot ^ (r & 7)) << 3);
    gload16(src, (const char*)vsb + (w*4 + p)*1024);
  }
}

__device__ __forceinline__ void proc_group(f32x4 (&sacc)[4], float (&m)[4], float (&l)[4],
    f32x4 (&o)[8], const int (&rq)[4], bool diag, int c0, int c16, int g,
    u16* Pw, const u16* vsb){
  const float scale = 0.08838834764831845f;
  float alpha[4];
  #pragma unroll
  for (int r = 0; r < 4; r++){
    float mx = -1e30f;
    #pragma unroll
    for (int nt = 0; nt < 4; nt++){
      float sv = sacc[nt][r] * scale;
      if (diag && (c0 + nt*16 + c16 > rq[r])) sv = -1e30f;
      sacc[nt][r] = sv;
      mx = fmaxf(mx, sv);
    }
    mx = fmaxf(mx, __shfl_xor(mx, 1));
    mx = fmaxf(mx, __shfl_xor(mx, 2));
    mx = fmaxf(mx, __shfl_xor(mx, 4));
    mx = fmaxf(mx, __shfl_xor(mx, 8));
    float mn = fmaxf(m[r], mx);
    alpha[r] = __expf(m[r] - mn);
    float sum = 0.f;
    #pragma unroll
    for (int nt = 0; nt < 4; nt++){
      float pv = __expf(sacc[nt][r] - mn);
      sacc[nt][r] = pv;
      sum += pv;
    }
    sum += __shfl_xor(sum, 1);
    sum += __shfl_xor(sum, 2);
    sum += __shfl_xor(sum, 4);
    sum += __shfl_xor(sum, 8);
    l[r] = l[r]*alpha[r] + sum;
    m[r] = mn;
  }
  #pragma unroll
  for (int dt = 0; dt < 8; dt++)
    #pragma unroll
    for (int r = 0; r < 4; r++) o[dt][r] *= alpha[r];
  // P -> per-wave LDS (8-elem-block XOR swizzle), then PV
  #pragma unroll
  for (int nt = 0; nt < 4; nt++){
    #pragma unroll
    for (int r = 0; r < 4; r++){
      int row = g*4 + r;
      int col = (nt*16 + c16) ^ ((row & 7) << 3);
      Pw[row*64 + col] = f2bf(sacc[nt][r]);
    }
  }
  #pragma unroll
  for (int kk2 = 0; kk2 < 2; kk2++){
    int cb = (kk2*4 + g) ^ (c16 & 7);
    bf16x8 pf = *(const bf16x8*)&Pw[c16*64 + cb*8];
    #pragma unroll
    for (int dt = 0; dt < 8; dt++){
      int d = dt*16 + c16;
      bf16x8 vf = *(const bf16x8*)&vsb[d*64 + (((kk2*4 + g) ^ (d & 7)) << 3)];
      o[dt] = mfma16(pf, vf, o[dt]);
    }
  }
}

__global__ __launch_bounds__(256, 2) void k_attn(const u16* __restrict__ q, const u16* __restrict__ k,
    const u16* __restrict__ vt, u16* __restrict__ attn){
  __shared__ u16 Ks[2][64*128];
  __shared__ u16 Vs[2][128*64];
  __shared__ u16 Pl[4][16*64];
  int lane = threadIdx.x & 63, w = threadIdx.x >> 6;
  int g = lane >> 4, c16 = lane & 15;
  // XCD-chunked decode: 512 blocks = 8 XCDs x 64; chunk = 4 hb (one kvh group) x 16 pairs
  int bid = blockIdx.x;
  int logical = (bid & 7)*64 + (bid >> 3);
  int pi = logical & 15;
  int hb = logical >> 4;
  int h = hb & 15, b = hb >> 4;
  int kvh = h >> 2;
  int qbA = pi*64, qbB = (31 - pi)*64;
  int tmax = 31 - pi;
  const u16* qp = q  + ((size_t)(b*16 + h))  * 2048 * 128;
  const u16* kp = k  + ((size_t)(b*4 + kvh)) * 2048 * 128;
  const u16* vp = vt + ((size_t)(b*4 + kvh)) * 128 * 2048;
  u16* Pw = Pl[w];

  int qrA = qbA + w*16 + c16, qrB = qbB + w*16 + c16;
  bf16x8 qfA[4], qfB[4];
  #pragma unroll
  for (int kk = 0; kk < 4; kk++){
    qfA[kk] = *(const bf16x8*)(qp + (size_t)qrA*128 + kk*32 + g*8);
    qfB[kk] = *(const bf16x8*)(qp + (size_t)qrB*128 + kk*32 + g*8);
  }
  asm volatile("s_waitcnt vmcnt(0)" ::: "memory");   // Q drained -> vmcnt counts staging only

  f32x4 zero = {0.f,0.f,0.f,0.f};
  f32x4 oA[8], oB[8];
  #pragma unroll
  for (int i=0;i<8;i++){ oA[i] = zero; oB[i] = zero; }
  float mA[4] = {-1e30f,-1e30f,-1e30f,-1e30f}, mB[4] = {-1e30f,-1e30f,-1e30f,-1e30f};
  float lA[4] = {0.f,0.f,0.f,0.f}, lB[4] = {0.f,0.f,0.f,0.f};
  int rqA[4], rqB[4];
  #pragma unroll
  for (int r=0;r<4;r++){ rqA[r] = qbA + w*16 + g*4 + r; rqB[r] = qbB + w*16 + g*4 + r; }

  stage_kv(w, lane, Ks[0], Vs[0], kp, vp, 0);   // 8 issues

  for (int t = 0; t <= tmax; t++){
    int c0 = t*64;
    if (t < tmax){
      stage_kv(w, lane, Ks[(t+1)&1], Vs[(t+1)&1], kp, vp, c0 + 64);  // 8 more in flight
      asm volatile("s_waitcnt vmcnt(8)" ::: "memory");  // tile t landed; t+1 stays in flight
    } else {
      asm volatile("s_waitcnt vmcnt(0)" ::: "memory");
    }
    __builtin_amdgcn_s_barrier();
    const u16* ksb = Ks[t&1];
    const u16* vsb = Vs[t&1];
    bool Aact = (t <= pi);
    f32x4 sA[4], sB[4];
    #pragma unroll
    for (int i=0;i<4;i++){ sA[i] = zero; sB[i] = zero; }
    if (Aact){
      #pragma unroll
      for (int nt=0;nt<4;nt++){
        #pragma unroll
        for (int kk=0;kk<4;kk++){
          int row = nt*16 + c16;
          bf16x8 kf = *(const bf16x8*)&ksb[row*128 + (((kk*4 + g) ^ (row & 7)) << 3)];
          sB[nt] = mfma16(qfB[kk], kf, sB[nt]);
          sA[nt] = mfma16(qfA[kk], kf, sA[nt]);
        }
      }
    } else {
      #pragma unroll
      for (int nt=0;nt<4;nt++){
        #pragma unroll
        for (int kk=0;kk<4;kk++){
          int row = nt*16 + c16;
          bf16x8 kf = *(const bf16x8*)&ksb[row*128 + (((kk*4 + g) ^ (row & 7)) << 3)];
          sB[nt] = mfma16(qfB[kk], kf, sB[nt]);
        }
      }
    }
    if (Aact) proc_group(sA, mA, lA, oA, rqA, t == pi, c0, c16, g, Pw, vsb);
    proc_group(sB, mB, lB, oB, rqB, t == tmax, c0, c16, g, Pw, vsb);
    __builtin_amdgcn_sched_barrier(0);
    asm volatile("s_waitcnt lgkmcnt(0)" ::: "memory"); // all LDS reads done before buffers recycle
    __builtin_amdgcn_s_barrier();
  }
  #pragma unroll
  for (int dt=0;dt<8;dt++){
    #pragma unroll
    for (int r=0;r<4;r++){
      size_t orA = (size_t)b*2048 + qbA + w*16 + g*4 + r;
      size_t orB = (size_t)b*2048 + qbB + w*16 + g*4 + r;
      attn[orA*2048 + (size_t)h*128 + dt*16 + c16] = f2bf(oA[dt][r] / lA[r]);
      attn[orB*2048 + (size_t)h*128 + dt*16 + c16] = f2bf(oB[dt][r] / lB[r]);
    }
  }
}

extern "C" void kernel_launch(void* const* d_in, const int* in_sizes, int n_in,
                              void* d_out, int out_size, void* d_ws, size_t ws_size,
                              hipStream_t stream){
  const float* hidden    = (const float*)d_in[0];
  const int*   positions = (const int*)d_in[1];
  const float* Wq = (const float*)d_in[2];
  const float* Wk = (const float*)d_in[3];
  const float* Wv = (const float*)d_in[4];
  const float* Wc = (const float*)d_in[5];
  const float* qs = (const float*)d_in[6];
  const float* ks = (const float*)d_in[7];
  float* out = (float*)d_out;
  char* ws = (char*)d_ws;
  float* ct      = (float*)(ws + 0);
  float* st      = (float*)(ws + 524288);
  u16*   hid_bf  = (u16*)(ws + 1048576);
  u16*   attn_bf = hid_bf;                    // reuse (dead after qkv GEMM)
  u16*   wqkv_t  = (u16*)(ws + 17825792);
  u16*   wct     = (u16*)(ws + 30408704);
  u16*   qkv_bf  = (u16*)(ws + 38797312);
  u16*   q_bf    = (u16*)(ws + 63963136);
  u16*   k_bf    = (u16*)(ws + 80740352);
  u16*   vt_bf   = (u16*)(ws + 84934656);

  k_rope_table<<<512, 256, 0, stream>>>(ct, st);
  k_cast_bf16<<<8192, 256, 0, stream>>>(hidden, hid_bf);
  k_trans_qkv<<<dim3(96, 64), dim3(32, 8), 0, stream>>>(Wq, Wk, Wv, wqkv_t);
  k_trans_wc<<<dim3(64, 64), dim3(32, 8), 0, stream>>>(Wc, wct);
  k_gemm<true><<<dim3(24, 32), 256, 0, stream>>>(hid_bf, wqkv_t, (void*)qkv_bf, 4096, 3072, 2048);
  k_norm_rope<<<dim3(4096, 24), 64, 0, stream>>>(qkv_bf, positions, qs, ks, ct, st, q_bf, k_bf, vt_bf);
  k_attn<<<512, 256, 0, stream>>>(q_bf, k_bf, vt_bf, attn_bf);
  k_gemm<false><<<dim3(16, 32), 256, 0, stream>>>(attn_bf, wct, (void*)out, 4096, 2048, 2048);
}